// Round 7
// baseline (96.609 us; speedup 1.0000x reference)
//
#include <hip/hip_runtime.h>
#include <hip/hip_bf16.h>
#include <math.h>

// UserHistoryTower on MI355X — 2 dispatches, no memset.
// R7 = R6 k_fused (256 blocks x 512 thr x 32 rows: per-block weight stream at
//      the aggregate-L2 optimum) + bucket build moved to LDS counters inside
//      k_prep block 0 (block zeroes its own LDS -> the 2KB global memset node
//      is gone; single pass, no scan, overlaps the 28 repack blocks).
//
// k_prep (29 x 1024):
//   block 0:    for each row j (grid-stride): if clk[j]:
//                 slot = atomicAdd(LDS cnt[user[j]]); bucket[u*64+slot]=(ts,j)
//               then dump cnt -> g_cnt. (order within bucket irrelevant: mean)
//   blocks 1-28: repack W1/W2/W3 (f32 [K][N]) -> bf16 MFMA B-fragment order,
//               one thread = one 16B chunk (coalesced bf16x8 store):
//               Wp[((f*(K/32)+k0c)*64+lane)*8+j] = W[k0c*32+q*8+j][f*16+c]
// k_fused (256 x 512): each block owns 32 rows (1 block/CU):
//   prefetch L1+L3 B-frags -> history gather (16 thr/row, all rows concurrent,
//   branchless 4-wide) -> L1 (128->512, SiLU) -> L2 (512->256, SiLU)
//   -> L3 (256->128) -> row L2-normalize + empty-row zero -> out.
//   Activations live in LDS (59 KB, O aliases dead regions).
// MFMA 16x16x32 bf16, layouts HW-verified (R1-R6 all passed):
//   A: lane holds A[m=c][k=q*8+j]; B: B[k=q*8+j][n=c]; C/D: row=q*4+r, col=c.

#define N_ROWS  8192
#define D_EMB   128
#define N_USERS 512
#define BUCKET  64

typedef __bf16 bf16;
typedef __bf16 bf16x8 __attribute__((ext_vector_type(8)));
typedef float  floatx4 __attribute__((ext_vector_type(4)));

__device__ __forceinline__ floatx4 mfma16(bf16x8 a, bf16x8 b, floatx4 c) {
    return __builtin_amdgcn_mfma_f32_16x16x32_bf16(a, b, c, 0, 0, 0);
}

// ---------------- k_prep ----------------

__global__ __launch_bounds__(1024) void k_prep(
    const int* __restrict__ user, const int* __restrict__ ts,
    const int* __restrict__ clk,
    const float* __restrict__ W1, const float* __restrict__ W2,
    const float* __restrict__ W3,
    bf16* __restrict__ Wp1, bf16* __restrict__ Wp2, bf16* __restrict__ Wp3,
    int* __restrict__ g_cnt, int2* __restrict__ g_bucket)
{
    const int bid = blockIdx.x, t = threadIdx.x;
    if (bid == 0) {
        // ---- bucket build with LDS counters (self-zeroed: no global memset) ----
        __shared__ int s_cnt[N_USERS];
        if (t < N_USERS) s_cnt[t] = 0;
        __syncthreads();
        for (int j = t; j < N_ROWS; j += 1024) {
            if (clk[j]) {
                int u = user[j];
                int slot = atomicAdd(&s_cnt[u], 1);
                if (slot < BUCKET)             // mean 8/user; cap 64 ~never hit
                    g_bucket[u * BUCKET + slot] = make_int2(ts[j], j);
            }
        }
        __syncthreads();
        if (t < N_USERS) g_cnt[t] = s_cnt[t];
        return;
    }
    // ---- weight repack: one thread = one 16B chunk (28672 chunks, 28 blocks) ----
    int gc = (bid - 1) * 1024 + t;
    const float* W; bf16* Wp; int K, N, chunk;
    if (gc < 8192)       { W = W1; Wp = Wp1; K = 128; N = 512; chunk = gc; }
    else if (gc < 24576) { W = W2; Wp = Wp2; K = 512; N = 256; chunk = gc - 8192; }
    else                 { W = W3; Wp = Wp3; K = 256; N = 128; chunk = gc - 24576; }
    int lane = chunk & 63, blk = chunk >> 6;
    int chunks_k = K >> 5;
    int f = blk / chunks_k, k0c = blk - f * chunks_k;
    int q = lane >> 4, c = lane & 15;
    const float* src = W + (size_t)(k0c * 32 + q * 8) * N + f * 16 + c;
    bf16x8 v;
    #pragma unroll
    for (int j = 0; j < 8; ++j) v[j] = (bf16)src[(size_t)j * N];
    *(bf16x8*)&Wp[(size_t)chunk * 8] = v;
}

// ---------------- k_fused ----------------

__global__ __launch_bounds__(512) void k_fused(
    const int* __restrict__ user, const int* __restrict__ ts,
    const float* __restrict__ ad,
    const int* __restrict__ g_cnt, const int2* __restrict__ g_bucket,
    const bf16* __restrict__ Wp1, const bf16* __restrict__ Wp2,
    const bf16* __restrict__ Wp3,
    const float* __restrict__ b1, const float* __restrict__ b2,
    const float* __restrict__ b3,
    float* __restrict__ out)
{
    // LDS (59 KB): Ah[32][136] | H1[32][520] | H2[32][264] | empty[32]
    // O[32][132] aliases Ah + head of H1 (dead by then).
    __shared__ __align__(16) char smem[59008];
    bf16 (*Ah)[136] = (bf16(*)[136])smem;                    //  8704 B
    bf16 (*H1)[520] = (bf16(*)[520])(smem + 8704);           // 33280 B
    bf16 (*H2)[264] = (bf16(*)[264])(smem + 8704 + 33280);   // 16896 B
    float (*O)[132] = (float(*)[132])smem;                   // 16896 B (alias)
    int* s_empty    = (int*)(smem + 58880);                  //   128 B

    const int t = threadIdx.x;
    const int w = t >> 6, lane = t & 63;
    const int q = lane >> 4, c = lane & 15;
    const int m0 = blockIdx.x * 32;

    // ---- prefetch L1 + L3 B-fragments (24 x 16B = 96 VGPRs) ----
    // these global loads issue before the history phase and overlap its latency
    bf16x8 pb1[4][4];
    #pragma unroll
    for (int cf = 0; cf < 4; ++cf)
        #pragma unroll
        for (int k0c = 0; k0c < 4; ++k0c)
            pb1[cf][k0c] = *(const bf16x8*)&Wp1[(size_t)(((w * 4 + cf) * 4 + k0c) * 64 + lane) * 8];
    bf16x8 pb3[8];
    #pragma unroll
    for (int k0c = 0; k0c < 8; ++k0c)
        pb3[k0c] = *(const bf16x8*)&Wp3[(size_t)((w * 8 + k0c) * 64 + lane) * 8];

    // ---- history: 16 threads/row, all 32 rows concurrent ----
    {
        const int row = t >> 4, dl = t & 15;
        const int i = m0 + row;
        const int u = user[i], myts = ts[i];
        int cnt = g_cnt[u]; cnt = (cnt > BUCKET) ? BUCKET : cnt;
        const int beg = u * BUCKET, end = beg + cnt;
        float a[8] = {0.f, 0.f, 0.f, 0.f, 0.f, 0.f, 0.f, 0.f};
        int m = 0;
        const float* adp = ad + (size_t)dl * 8;
        for (int p = beg; p < end; p += 4) {
            #pragma unroll
            for (int kk = 0; kk < 4; ++kk) {
                int pp = p + kk;
                int ppc = (pp < end) ? pp : end - 1;       // end>beg inside loop
                int2 it = g_bucket[ppc];
                bool ok = (pp < end) & (it.x < myts);      // strict: ts_i > ts_j
                const float4* r = (const float4*)(adp + (size_t)it.y * D_EMB);
                float4 v0 = r[0], v1 = r[1];
                float s = ok ? 1.f : 0.f;
                a[0] += s * v0.x; a[1] += s * v0.y; a[2] += s * v0.z; a[3] += s * v0.w;
                a[4] += s * v1.x; a[5] += s * v1.y; a[6] += s * v1.z; a[7] += s * v1.w;
                m += ok ? 1 : 0;
            }
        }
        float inv = m ? 1.f / (float)m : 0.f;              // ref: /(cnt+1e-16)
        bf16x8 hv;
        #pragma unroll
        for (int j = 0; j < 8; ++j) hv[j] = (bf16)(a[j] * inv);
        *(bf16x8*)&Ah[row][dl * 8] = hv;
        if (dl == 0) s_empty[row] = (m == 0);
    }
    __syncthreads();

    // ---- L1: 128 -> 512, SiLU. Wave owns cols [w*64, w*64+64) ----
    {
        floatx4 acc[4][2];
        #pragma unroll
        for (int cf = 0; cf < 4; ++cf)
            #pragma unroll
            for (int mi = 0; mi < 2; ++mi)
                acc[cf][mi] = (floatx4){0.f, 0.f, 0.f, 0.f};
        #pragma unroll
        for (int k0c = 0; k0c < 4; ++k0c) {
            bf16x8 a0 = *(const bf16x8*)&Ah[c][k0c * 32 + q * 8];
            bf16x8 a1 = *(const bf16x8*)&Ah[16 + c][k0c * 32 + q * 8];
            #pragma unroll
            for (int cf = 0; cf < 4; ++cf) {
                acc[cf][0] = mfma16(a0, pb1[cf][k0c], acc[cf][0]);
                acc[cf][1] = mfma16(a1, pb1[cf][k0c], acc[cf][1]);
            }
        }
        #pragma unroll
        for (int cf = 0; cf < 4; ++cf) {
            const int col = w * 64 + cf * 16 + c;
            const float bb = b1[col];
            #pragma unroll
            for (int mi = 0; mi < 2; ++mi)
                #pragma unroll
                for (int r = 0; r < 4; ++r) {
                    float v = acc[cf][mi][r] + bb;
                    v = v / (1.f + __expf(-v));            // SiLU
                    H1[mi * 16 + q * 4 + r][col] = (bf16)v;
                }
        }
    }
    __syncthreads();

    // ---- L2: 512 -> 256, SiLU. Wave owns cols [w*32, w*32+32) ----
    {
        floatx4 acc[2][2];
        #pragma unroll
        for (int cf = 0; cf < 2; ++cf)
            #pragma unroll
            for (int mi = 0; mi < 2; ++mi)
                acc[cf][mi] = (floatx4){0.f, 0.f, 0.f, 0.f};
        #pragma unroll 4
        for (int k0c = 0; k0c < 16; ++k0c) {
            bf16x8 a0 = *(const bf16x8*)&H1[c][k0c * 32 + q * 8];
            bf16x8 a1 = *(const bf16x8*)&H1[16 + c][k0c * 32 + q * 8];
            #pragma unroll
            for (int cf = 0; cf < 2; ++cf) {
                bf16x8 b = *(const bf16x8*)&Wp2[(size_t)(((w * 2 + cf) * 16 + k0c) * 64 + lane) * 8];
                acc[cf][0] = mfma16(a0, b, acc[cf][0]);
                acc[cf][1] = mfma16(a1, b, acc[cf][1]);
            }
        }
        #pragma unroll
        for (int cf = 0; cf < 2; ++cf) {
            const int col = w * 32 + cf * 16 + c;
            const float bb = b2[col];
            #pragma unroll
            for (int mi = 0; mi < 2; ++mi)
                #pragma unroll
                for (int r = 0; r < 4; ++r) {
                    float v = acc[cf][mi][r] + bb;
                    v = v / (1.f + __expf(-v));
                    H2[mi * 16 + q * 4 + r][col] = (bf16)v;
                }
        }
    }
    __syncthreads();

    // ---- L3: 256 -> 128 (no act). Wave owns cols [w*16, w*16+16) ----
    {
        floatx4 acc0 = (floatx4){0.f, 0.f, 0.f, 0.f};
        floatx4 acc1 = (floatx4){0.f, 0.f, 0.f, 0.f};
        #pragma unroll
        for (int k0c = 0; k0c < 8; ++k0c) {
            bf16x8 a0 = *(const bf16x8*)&H2[c][k0c * 32 + q * 8];
            bf16x8 a1 = *(const bf16x8*)&H2[16 + c][k0c * 32 + q * 8];
            acc0 = mfma16(a0, pb3[k0c], acc0);
            acc1 = mfma16(a1, pb3[k0c], acc1);
        }
        const int col = w * 16 + c;
        const float bb = b3[col];
        #pragma unroll
        for (int r = 0; r < 4; ++r) {
            O[q * 4 + r][col]      = acc0[r] + bb;
            O[16 + q * 4 + r][col] = acc1[r] + bb;
        }
    }
    __syncthreads();

    // ---- L2-normalize rows + empty-zero, write out ----
    {
        const int row = t >> 4, s = t & 15;        // 16 threads/row, 8 cols each
        float v[8];
        const float* orow = &O[row][s * 8];
        float ss = 0.f;
        #pragma unroll
        for (int j = 0; j < 8; ++j) { v[j] = orow[j]; ss += v[j] * v[j]; }
        ss += __shfl_xor(ss, 1);
        ss += __shfl_xor(ss, 2);
        ss += __shfl_xor(ss, 4);
        ss += __shfl_xor(ss, 8);
        // x/max(||x||,1e-16) twice == once; empty rows -> 0
        float scale = s_empty[row] ? 0.f : 1.f / fmaxf(sqrtf(ss), 1e-16f);
        float4 o0 = {v[0] * scale, v[1] * scale, v[2] * scale, v[3] * scale};
        float4 o1 = {v[4] * scale, v[5] * scale, v[6] * scale, v[7] * scale};
        float* dst = out + (size_t)(m0 + row) * D_EMB + s * 8;
        *(float4*)dst       = o0;
        *(float4*)(dst + 4) = o1;
    }
}

// ---------------- launcher ----------------

extern "C" void kernel_launch(void* const* d_in, const int* in_sizes, int n_in,
                              void* d_out, int out_size, void* d_ws, size_t ws_size,
                              hipStream_t stream) {
    const float* ad   = (const float*)d_in[0];
    const int*   user = (const int*)d_in[1];
    const int*   ts   = (const int*)d_in[2];
    const int*   clk  = (const int*)d_in[3];
    const float* W1 = (const float*)d_in[4];
    const float* b1 = (const float*)d_in[5];
    const float* W2 = (const float*)d_in[6];
    const float* b2 = (const float*)d_in[7];
    const float* W3 = (const float*)d_in[8];
    const float* b3 = (const float*)d_in[9];
    float* out = (float*)d_out;
    (void)in_sizes; (void)n_in; (void)out_size; (void)ws_size;

    char* ws = (char*)d_ws;
    bf16* Wp1      = (bf16*)(ws);                   // 131072 B
    bf16* Wp2      = (bf16*)(ws + 131072);          // 262144 B
    bf16* Wp3      = (bf16*)(ws + 393216);          //  65536 B
    int*  g_cnt    = (int*) (ws + 458752);          //   2048 B
    int2* g_bucket = (int2*)(ws + 460800);          // 262144 B (512 users x 64 x 8B)

    k_prep <<<dim3(29), dim3(1024), 0, stream>>>(user, ts, clk, W1, W2, W3,
                                                 Wp1, Wp2, Wp3, g_cnt, g_bucket);
    k_fused<<<dim3(N_ROWS / 32), dim3(512), 0, stream>>>(user, ts, ad,
                                                         g_cnt, g_bucket,
                                                         Wp1, Wp2, Wp3,
                                                         b1, b2, b3, out);
}

// Round 8
// 92.017 us; speedup vs baseline: 1.0499x; 1.0499x over previous
//
#include <hip/hip_runtime.h>
#include <hip/hip_bf16.h>
#include <math.h>

// UserHistoryTower on MI355X — memset + 2 dispatches (R6 structure, best
// measured 93.3us; R7's centralized scatter regressed +3.3us — reverted).
// R8 delta: prefetch first half of Wp2 alongside Wp1/Wp3 so ~75% of the
// 448 KB/block weight stream overlaps the history-gather latency window.
//
// hipMemsetAsync: zero cnt[512] (harness poisons ws to 0xAA each call).
// k_prep (36 x 1024, flat task id):
//   tasks 0..8191:      if clk[j]: slot=atomicAdd(cnt[user]); bucket[u*64+slot]=(ts,j)
//   tasks 8192..36863:  repack W1/W2/W3 (f32 [K][N]) -> bf16 MFMA B-fragment
//                       order, one thread = one 16B chunk (coalesced bf16x8
//                       store): Wp[((f*(K/32)+k0c)*64+lane)*8+j] = W[k0c*32+q*8+j][f*16+c]
// k_fused (256 x 512): each block owns 32 rows (1 block/CU):
//   prefetch L1+L3+half-L2 B-frags -> history gather (16 thr/row, all rows
//   concurrent, branchless 4-wide) -> L1 (128->512, SiLU) -> L2 (512->256,
//   SiLU) -> L3 (256->128) -> row L2-normalize + empty-row zero -> out.
//   Activations live in LDS (59 KB, O aliases dead regions).
// MFMA 16x16x32 bf16, layouts HW-verified (R1-R7 all passed):
//   A: lane holds A[m=c][k=q*8+j]; B: B[k=q*8+j][n=c]; C/D: row=q*4+r, col=c.

#define N_ROWS  8192
#define D_EMB   128
#define N_USERS 512
#define BUCKET  64

typedef __bf16 bf16;
typedef __bf16 bf16x8 __attribute__((ext_vector_type(8)));
typedef float  floatx4 __attribute__((ext_vector_type(4)));

__device__ __forceinline__ floatx4 mfma16(bf16x8 a, bf16x8 b, floatx4 c) {
    return __builtin_amdgcn_mfma_f32_16x16x32_bf16(a, b, c, 0, 0, 0);
}

// ---------------- k_prep ----------------

__global__ __launch_bounds__(1024) void k_prep(
    const int* __restrict__ user, const int* __restrict__ ts,
    const int* __restrict__ clk,
    const float* __restrict__ W1, const float* __restrict__ W2,
    const float* __restrict__ W3,
    bf16* __restrict__ Wp1, bf16* __restrict__ Wp2, bf16* __restrict__ Wp3,
    int* __restrict__ g_cnt, int2* __restrict__ g_bucket)
{
    int g = blockIdx.x * 1024 + threadIdx.x;   // 0 .. 36863
    if (g < N_ROWS) {
        // ---- bucket scatter: one thread per row, distributed across blocks ----
        if (clk[g]) {
            int u = user[g];
            int slot = atomicAdd(&g_cnt[u], 1);
            if (slot < BUCKET)                 // mean 8/user; cap 64 ~never hit
                g_bucket[u * BUCKET + slot] = make_int2(ts[g], g);
        }
        return;
    }
    // ---- weight repack: one thread = one 16B chunk (28672 chunks) ----
    int gc = g - N_ROWS;
    const float* W; bf16* Wp; int K, N, chunk;
    if (gc < 8192)       { W = W1; Wp = Wp1; K = 128; N = 512; chunk = gc; }
    else if (gc < 24576) { W = W2; Wp = Wp2; K = 512; N = 256; chunk = gc - 8192; }
    else                 { W = W3; Wp = Wp3; K = 256; N = 128; chunk = gc - 24576; }
    int lane = chunk & 63, blk = chunk >> 6;
    int chunks_k = K >> 5;
    int f = blk / chunks_k, k0c = blk - f * chunks_k;
    int q = lane >> 4, c = lane & 15;
    const float* src = W + (size_t)(k0c * 32 + q * 8) * N + f * 16 + c;
    bf16x8 v;
    #pragma unroll
    for (int j = 0; j < 8; ++j) v[j] = (bf16)src[(size_t)j * N];
    *(bf16x8*)&Wp[(size_t)chunk * 8] = v;
}

// ---------------- k_fused ----------------

__global__ __launch_bounds__(512) void k_fused(
    const int* __restrict__ user, const int* __restrict__ ts,
    const float* __restrict__ ad,
    const int* __restrict__ g_cnt, const int2* __restrict__ g_bucket,
    const bf16* __restrict__ Wp1, const bf16* __restrict__ Wp2,
    const bf16* __restrict__ Wp3,
    const float* __restrict__ b1, const float* __restrict__ b2,
    const float* __restrict__ b3,
    float* __restrict__ out)
{
    // LDS (59 KB): Ah[32][136] | H1[32][520] | H2[32][264] | empty[32]
    // O[32][132] aliases Ah + head of H1 (dead by then).
    __shared__ __align__(16) char smem[59008];
    bf16 (*Ah)[136] = (bf16(*)[136])smem;                    //  8704 B
    bf16 (*H1)[520] = (bf16(*)[520])(smem + 8704);           // 33280 B
    bf16 (*H2)[264] = (bf16(*)[264])(smem + 8704 + 33280);   // 16896 B
    float (*O)[132] = (float(*)[132])smem;                   // 16896 B (alias)
    int* s_empty    = (int*)(smem + 58880);                  //   128 B

    const int t = threadIdx.x;
    const int w = t >> 6, lane = t & 63;
    const int q = lane >> 4, c = lane & 15;
    const int m0 = blockIdx.x * 32;

    // ---- prefetch L1 + L3 + first-half L2 B-fragments (40 x 16B = 160 VGPRs)
    // all issue before the history phase and overlap its gather latency
    bf16x8 pb1[4][4];
    #pragma unroll
    for (int cf = 0; cf < 4; ++cf)
        #pragma unroll
        for (int k0c = 0; k0c < 4; ++k0c)
            pb1[cf][k0c] = *(const bf16x8*)&Wp1[(size_t)(((w * 4 + cf) * 4 + k0c) * 64 + lane) * 8];
    bf16x8 pb3[8];
    #pragma unroll
    for (int k0c = 0; k0c < 8; ++k0c)
        pb3[k0c] = *(const bf16x8*)&Wp3[(size_t)((w * 8 + k0c) * 64 + lane) * 8];
    bf16x8 pb2a[2][8];
    #pragma unroll
    for (int cf = 0; cf < 2; ++cf)
        #pragma unroll
        for (int k0c = 0; k0c < 8; ++k0c)
            pb2a[cf][k0c] = *(const bf16x8*)&Wp2[(size_t)(((w * 2 + cf) * 16 + k0c) * 64 + lane) * 8];

    // ---- history: 16 threads/row, all 32 rows concurrent ----
    {
        const int row = t >> 4, dl = t & 15;
        const int i = m0 + row;
        const int u = user[i], myts = ts[i];
        int cnt = g_cnt[u]; cnt = (cnt > BUCKET) ? BUCKET : cnt;
        const int beg = u * BUCKET, end = beg + cnt;
        float a[8] = {0.f, 0.f, 0.f, 0.f, 0.f, 0.f, 0.f, 0.f};
        int m = 0;
        const float* adp = ad + (size_t)dl * 8;
        for (int p = beg; p < end; p += 4) {
            #pragma unroll
            for (int kk = 0; kk < 4; ++kk) {
                int pp = p + kk;
                int ppc = (pp < end) ? pp : end - 1;       // end>beg inside loop
                int2 it = g_bucket[ppc];
                bool ok = (pp < end) & (it.x < myts);      // strict: ts_i > ts_j
                const float4* r = (const float4*)(adp + (size_t)it.y * D_EMB);
                float4 v0 = r[0], v1 = r[1];
                float s = ok ? 1.f : 0.f;
                a[0] += s * v0.x; a[1] += s * v0.y; a[2] += s * v0.z; a[3] += s * v0.w;
                a[4] += s * v1.x; a[5] += s * v1.y; a[6] += s * v1.z; a[7] += s * v1.w;
                m += ok ? 1 : 0;
            }
        }
        float inv = m ? 1.f / (float)m : 0.f;              // ref: /(cnt+1e-16)
        bf16x8 hv;
        #pragma unroll
        for (int j = 0; j < 8; ++j) hv[j] = (bf16)(a[j] * inv);
        *(bf16x8*)&Ah[row][dl * 8] = hv;
        if (dl == 0) s_empty[row] = (m == 0);
    }
    __syncthreads();

    // ---- L1: 128 -> 512, SiLU. Wave owns cols [w*64, w*64+64) ----
    {
        floatx4 acc[4][2];
        #pragma unroll
        for (int cf = 0; cf < 4; ++cf)
            #pragma unroll
            for (int mi = 0; mi < 2; ++mi)
                acc[cf][mi] = (floatx4){0.f, 0.f, 0.f, 0.f};
        #pragma unroll
        for (int k0c = 0; k0c < 4; ++k0c) {
            bf16x8 a0 = *(const bf16x8*)&Ah[c][k0c * 32 + q * 8];
            bf16x8 a1 = *(const bf16x8*)&Ah[16 + c][k0c * 32 + q * 8];
            #pragma unroll
            for (int cf = 0; cf < 4; ++cf) {
                acc[cf][0] = mfma16(a0, pb1[cf][k0c], acc[cf][0]);
                acc[cf][1] = mfma16(a1, pb1[cf][k0c], acc[cf][1]);
            }
        }
        #pragma unroll
        for (int cf = 0; cf < 4; ++cf) {
            const int col = w * 64 + cf * 16 + c;
            const float bb = b1[col];
            #pragma unroll
            for (int mi = 0; mi < 2; ++mi)
                #pragma unroll
                for (int r = 0; r < 4; ++r) {
                    float v = acc[cf][mi][r] + bb;
                    v = v / (1.f + __expf(-v));            // SiLU
                    H1[mi * 16 + q * 4 + r][col] = (bf16)v;
                }
        }
    }
    __syncthreads();

    // ---- L2: 512 -> 256, SiLU. Wave owns cols [w*32, w*32+32) ----
    {
        floatx4 acc[2][2];
        #pragma unroll
        for (int cf = 0; cf < 2; ++cf)
            #pragma unroll
            for (int mi = 0; mi < 2; ++mi)
                acc[cf][mi] = (floatx4){0.f, 0.f, 0.f, 0.f};
        #pragma unroll
        for (int k0c = 0; k0c < 16; ++k0c) {
            bf16x8 a0 = *(const bf16x8*)&H1[c][k0c * 32 + q * 8];
            bf16x8 a1 = *(const bf16x8*)&H1[16 + c][k0c * 32 + q * 8];
            #pragma unroll
            for (int cf = 0; cf < 2; ++cf) {
                bf16x8 b = (k0c < 8)
                    ? pb2a[cf][k0c & 7]
                    : *(const bf16x8*)&Wp2[(size_t)(((w * 2 + cf) * 16 + k0c) * 64 + lane) * 8];
                acc[cf][0] = mfma16(a0, b, acc[cf][0]);
                acc[cf][1] = mfma16(a1, b, acc[cf][1]);
            }
        }
        #pragma unroll
        for (int cf = 0; cf < 2; ++cf) {
            const int col = w * 32 + cf * 16 + c;
            const float bb = b2[col];
            #pragma unroll
            for (int mi = 0; mi < 2; ++mi)
                #pragma unroll
                for (int r = 0; r < 4; ++r) {
                    float v = acc[cf][mi][r] + bb;
                    v = v / (1.f + __expf(-v));
                    H2[mi * 16 + q * 4 + r][col] = (bf16)v;
                }
        }
    }
    __syncthreads();

    // ---- L3: 256 -> 128 (no act). Wave owns cols [w*16, w*16+16) ----
    {
        floatx4 acc0 = (floatx4){0.f, 0.f, 0.f, 0.f};
        floatx4 acc1 = (floatx4){0.f, 0.f, 0.f, 0.f};
        #pragma unroll
        for (int k0c = 0; k0c < 8; ++k0c) {
            bf16x8 a0 = *(const bf16x8*)&H2[c][k0c * 32 + q * 8];
            bf16x8 a1 = *(const bf16x8*)&H2[16 + c][k0c * 32 + q * 8];
            acc0 = mfma16(a0, pb3[k0c], acc0);
            acc1 = mfma16(a1, pb3[k0c], acc1);
        }
        const int col = w * 16 + c;
        const float bb = b3[col];
        #pragma unroll
        for (int r = 0; r < 4; ++r) {
            O[q * 4 + r][col]      = acc0[r] + bb;
            O[16 + q * 4 + r][col] = acc1[r] + bb;
        }
    }
    __syncthreads();

    // ---- L2-normalize rows + empty-zero, write out ----
    {
        const int row = t >> 4, s = t & 15;        // 16 threads/row, 8 cols each
        float v[8];
        const float* orow = &O[row][s * 8];
        float ss = 0.f;
        #pragma unroll
        for (int j = 0; j < 8; ++j) { v[j] = orow[j]; ss += v[j] * v[j]; }
        ss += __shfl_xor(ss, 1);
        ss += __shfl_xor(ss, 2);
        ss += __shfl_xor(ss, 4);
        ss += __shfl_xor(ss, 8);
        // x/max(||x||,1e-16) twice == once; empty rows -> 0
        float scale = s_empty[row] ? 0.f : 1.f / fmaxf(sqrtf(ss), 1e-16f);
        float4 o0 = {v[0] * scale, v[1] * scale, v[2] * scale, v[3] * scale};
        float4 o1 = {v[4] * scale, v[5] * scale, v[6] * scale, v[7] * scale};
        float* dst = out + (size_t)(m0 + row) * D_EMB + s * 8;
        *(float4*)dst       = o0;
        *(float4*)(dst + 4) = o1;
    }
}

// ---------------- launcher ----------------

extern "C" void kernel_launch(void* const* d_in, const int* in_sizes, int n_in,
                              void* d_out, int out_size, void* d_ws, size_t ws_size,
                              hipStream_t stream) {
    const float* ad   = (const float*)d_in[0];
    const int*   user = (const int*)d_in[1];
    const int*   ts   = (const int*)d_in[2];
    const int*   clk  = (const int*)d_in[3];
    const float* W1 = (const float*)d_in[4];
    const float* b1 = (const float*)d_in[5];
    const float* W2 = (const float*)d_in[6];
    const float* b2 = (const float*)d_in[7];
    const float* W3 = (const float*)d_in[8];
    const float* b3 = (const float*)d_in[9];
    float* out = (float*)d_out;
    (void)in_sizes; (void)n_in; (void)out_size; (void)ws_size;

    char* ws = (char*)d_ws;
    bf16* Wp1      = (bf16*)(ws);                   // 131072 B
    bf16* Wp2      = (bf16*)(ws + 131072);          // 262144 B
    bf16* Wp3      = (bf16*)(ws + 393216);          //  65536 B
    int*  g_cnt    = (int*) (ws + 458752);          //   2048 B
    int2* g_bucket = (int2*)(ws + 460800);          // 262144 B (512 users x 64 x 8B)

    hipMemsetAsync(g_cnt, 0, N_USERS * sizeof(int), stream);

    k_prep <<<dim3(36), dim3(1024), 0, stream>>>(user, ts, clk, W1, W2, W3,
                                                 Wp1, Wp2, Wp3, g_cnt, g_bucket);
    k_fused<<<dim3(N_ROWS / 32), dim3(512), 0, stream>>>(user, ts, ad,
                                                         g_cnt, g_bucket,
                                                         Wp1, Wp2, Wp3,
                                                         b1, b2, b3, out);
}